// Round 17
// baseline (313.060 us; speedup 1.0000x reference)
//
#include <hip/hip_runtime.h>
#include <math.h>
#include <stdint.h>

typedef __bf16 bf16x8_t __attribute__((ext_vector_type(8)));
typedef float  f32x4_t  __attribute__((ext_vector_type(4)));
typedef unsigned short u16;

// ---- helpers -------------------------------------------------------------

__device__ __forceinline__ u16 f2bf(float f) {
  unsigned u = __float_as_uint(f);
  u += 0x7FFFu + ((u >> 16) & 1u);
  return (u16)(u >> 16);
}

// native bf16 convert (RNE) — 1 VALU op vs f2bf's 3
__device__ __forceinline__ u16 bf16bits(float f) {
  __bf16 b = (__bf16)f;
  return __builtin_bit_cast(u16, b);
}

__device__ __forceinline__ void gload_lds16(const u16* gsrc, u16* ldst) {
  // async global->LDS, 16B per lane; LDS dest = wave-uniform base + lane*16
  __builtin_amdgcn_global_load_lds(
      (__attribute__((address_space(1))) void*)(const_cast<u16*>(gsrc)),
      (__attribute__((address_space(3))) void*)(ldst),
      16, 0, 0);
}

// XOR swizzle for 128B rows (64 bf16): byte ^= ((row&7)<<4) == elem ^= ((row&7)<<3)
__device__ __forceinline__ int sw8(int row, int e) { return e ^ ((row & 7) << 3); }

__device__ __forceinline__ void store_out(float* C, long idx, float v) { C[idx] = v; }
__device__ __forceinline__ void store_out(u16* C, long idx, float v) { C[idx] = f2bf(v); }

__device__ __forceinline__ float alibi_slope(int h, int H) {
  int cp2 = 1, lg = 0;
  while (cp2 * 2 <= H) { cp2 *= 2; lg++; }
  if (h < cp2) {
    double e = exp2((double)-(lg - 3));
    return (float)exp2(-e * (double)(h + 1));
  } else {
    double e = exp2((double)-(lg + 1 - 3));
    return (float)exp2(-e * (double)(2 * (h - cp2) + 1));
  }
}

#define FENCE() asm volatile("" ::: "memory")
#define BARRIER() do { FENCE(); __builtin_amdgcn_s_barrier(); \
                       __builtin_amdgcn_sched_barrier(0); FENCE(); } while (0)
#define WAITLGKM() do { asm volatile("s_waitcnt lgkmcnt(0)" ::: "memory"); \
                        __builtin_amdgcn_sched_barrier(0); } while (0)

// ---- elementwise cast f32 -> bf16 ---------------------------------------

__global__ __launch_bounds__(256) void k_cast_bf16(const float* __restrict__ in,
                                                   u16* __restrict__ out, long n) {
  long i = ((long)blockIdx.x * 256 + threadIdx.x) * 4;
  if (i + 3 < n) {
    float4 v = *reinterpret_cast<const float4*>(in + i);
    ushort4 o;
    o.x = f2bf(v.x); o.y = f2bf(v.y); o.z = f2bf(v.z); o.w = f2bf(v.w);
    *reinterpret_cast<ushort4*>(out + i) = o;
  }
}

// ---- transpose + cast (merged): z<3 -> qkvw[z], z==3 -> ow ----------------

__global__ __launch_bounds__(256) void k_transpose_cast4(const float* __restrict__ in0,
                                                         const float* __restrict__ in1,
                                                         u16* __restrict__ out,
                                                         int R, int C) {
  __shared__ float tile[32][33];
  const float* inz = (blockIdx.z < 3) ? (in0 + (long)blockIdx.z * R * C) : in1;
  u16* outz = out + (long)blockIdx.z * R * C;
  const int tx = threadIdx.x & 31, ty = threadIdx.x >> 5;
  const int r0 = blockIdx.y * 32, c0 = blockIdx.x * 32;
#pragma unroll
  for (int i = 0; i < 4; ++i)
    tile[ty + i * 8][tx] = inz[(long)(r0 + ty + i * 8) * C + c0 + tx];
  __syncthreads();
#pragma unroll
  for (int i = 0; i < 4; ++i)
    outz[(long)(c0 + ty + i * 8) * R + r0 + tx] = f2bf(tile[tx][ty + i * 8]);
}

// ---- staging helpers (linear LDS dest + inverse-swizzled global source) --

__device__ __forceinline__ void stage16(const u16* __restrict__ g, long grow0, int K,
                                        int kt, int lr0, u16 (*lds)[64], int lane) {
  const int e = (lane & 7) * 8;
#pragma unroll
  for (int i = 0; i < 2; ++i) {
    const int r = lr0 + i * 8 + (lane >> 3);
    gload_lds16(g + (grow0 + r) * (long)K + kt + (e ^ ((r & 7) << 3)), &lds[lr0 + i * 8][0]);
  }
}

__device__ __forceinline__ void stage8(const u16* __restrict__ g, long grow0, int K,
                                       int kt, int lr0, u16 (*lds)[64], int lane) {
  const int e = (lane & 7) * 8;
  const int r = lr0 + (lane >> 3);
  gload_lds16(g + (grow0 + r) * (long)K + kt + (e ^ ((r & 7) << 3)), &lds[lr0][0]);
}

// ---- 256x256 4-phase bf16 GEMM (QKV) + fused V-transpose epilogue --------

template <typename OUT_T>
__global__ __launch_bounds__(512, 2) void k_gemm8(const u16* __restrict__ A,
                                                  const u16* __restrict__ Bt,
                                                  OUT_T* __restrict__ Cb,
                                                  int M, int N, int K, long matStride,
                                                  float qs, u16* __restrict__ Vt) {
  __shared__ u16 As[2][256][64];
  __shared__ u16 Bs[2][256][64];

  const int tid = threadIdx.x, wid = tid >> 6, lane = tid & 63;
  const int wr = wid >> 2, wc = wid & 3;
  const int frow = lane & 15, fk8 = (lane >> 4) * 8;
  const int orow = (lane >> 4) * 4, ocol = lane & 15;

  const int nwg = gridDim.x * gridDim.y;
  const int orig = blockIdx.y * gridDim.x + blockIdx.x;
  const int q = nwg >> 3, rr = nwg & 7;
  const int xcd = orig & 7, sl = orig >> 3;
  const int wg = (xcd < rr ? xcd * (q + 1) : rr * (q + 1) + (xcd - rr) * q) + sl;
  const int by = wg / gridDim.x, bx = wg % gridDim.x;

  const long abase = (long)by * 256, bbase = (long)bx * 256;

  const int bg0 = (wid >> 1) * 64 + (wid & 1) * 16;
  const int ag0 = (wid >> 2) * 128 + (wid & 3) * 16;

  f32x4_t acc[8][4];
#pragma unroll
  for (int m = 0; m < 8; ++m)
#pragma unroll
    for (int n = 0; n < 4; ++n)
#pragma unroll
      for (int r = 0; r < 4; ++r) acc[m][n][r] = 0.f;

  const int nt = K >> 6;

  stage16(A, abase, K, 0, ag0, As[0], lane);
  stage16(Bt, bbase, K, 0, bg0, Bs[0], lane);
  stage16(Bt, bbase, K, 0, bg0 + 32, Bs[0], lane);
  stage16(A, abase, K, 0, ag0 + 64, As[0], lane);
  asm volatile("s_waitcnt vmcnt(4)" ::: "memory");
  BARRIER();

  bf16x8_t afr[4][2], bfr[4][2];
  int cur = 0;

  for (int t = 0; t < nt; ++t) {
    const int ktn = (t + 1) << 6;
    const bool hn = (t + 1 < nt);
    const int nb = cur ^ 1;

    // ---- phase 1: quadrant (mh0,nh0); stage A-h0(t+1)
#pragma unroll
    for (int m = 0; m < 4; ++m) {
      const int r = wr * 128 + m * 16 + frow;
      afr[m][0] = *reinterpret_cast<const bf16x8_t*>(&As[cur][r][sw8(r, fk8)]);
      afr[m][1] = *reinterpret_cast<const bf16x8_t*>(&As[cur][r][sw8(r, 32 + fk8)]);
    }
#pragma unroll
    for (int n = 0; n < 2; ++n) {
      const int r = wc * 64 + n * 16 + frow;
      bfr[n][0] = *reinterpret_cast<const bf16x8_t*>(&Bs[cur][r][sw8(r, fk8)]);
      bfr[n][1] = *reinterpret_cast<const bf16x8_t*>(&Bs[cur][r][sw8(r, 32 + fk8)]);
    }
    if (hn) stage16(A, abase, K, ktn, ag0, As[nb], lane);
    BARRIER();
    WAITLGKM();
    __builtin_amdgcn_s_setprio(1);
#pragma unroll
    for (int m = 0; m < 4; ++m)
#pragma unroll
      for (int n = 0; n < 2; ++n) {
        acc[m][n] = __builtin_amdgcn_mfma_f32_16x16x32_bf16(afr[m][0], bfr[n][0], acc[m][n], 0, 0, 0);
        acc[m][n] = __builtin_amdgcn_mfma_f32_16x16x32_bf16(afr[m][1], bfr[n][1], acc[m][n], 0, 0, 0);
      }
    __builtin_amdgcn_s_setprio(0);
    if (hn) asm volatile("s_waitcnt vmcnt(4)" ::: "memory");
    else    asm volatile("s_waitcnt vmcnt(2)" ::: "memory");
    BARRIER();

    // ---- phase 2: quadrant (mh0,nh1); stage B-h0(t+1)
#pragma unroll
    for (int n = 0; n < 2; ++n) {
      const int r = wc * 64 + 32 + n * 16 + frow;
      bfr[2 + n][0] = *reinterpret_cast<const bf16x8_t*>(&Bs[cur][r][sw8(r, fk8)]);
      bfr[2 + n][1] = *reinterpret_cast<const bf16x8_t*>(&Bs[cur][r][sw8(r, 32 + fk8)]);
    }
    if (hn) stage16(Bt, bbase, K, ktn, bg0, Bs[nb], lane);
    BARRIER();
    WAITLGKM();
    __builtin_amdgcn_s_setprio(1);
#pragma unroll
    for (int m = 0; m < 4; ++m)
#pragma unroll
      for (int n = 0; n < 2; ++n) {
        acc[m][2 + n] = __builtin_amdgcn_mfma_f32_16x16x32_bf16(afr[m][0], bfr[2 + n][0], acc[m][2 + n], 0, 0, 0);
        acc[m][2 + n] = __builtin_amdgcn_mfma_f32_16x16x32_bf16(afr[m][1], bfr[2 + n][1], acc[m][2 + n], 0, 0, 0);
      }
    __builtin_amdgcn_s_setprio(0);
    if (!hn) asm volatile("s_waitcnt vmcnt(0)" ::: "memory");
    BARRIER();

    // ---- phase 3: quadrant (mh1,nh0); stage B-h1(t+1)
#pragma unroll
    for (int m = 0; m < 4; ++m) {
      const int r = wr * 128 + 64 + m * 16 + frow;
      afr[m][0] = *reinterpret_cast<const bf16x8_t*>(&As[cur][r][sw8(r, fk8)]);
      afr[m][1] = *reinterpret_cast<const bf16x8_t*>(&As[cur][r][sw8(r, 32 + fk8)]);
    }
    if (hn) stage16(Bt, bbase, K, ktn, bg0 + 32, Bs[nb], lane);
    BARRIER();
    WAITLGKM();
    __builtin_amdgcn_s_setprio(1);
#pragma unroll
    for (int m = 0; m < 4; ++m)
#pragma unroll
      for (int n = 0; n < 2; ++n) {
        acc[4 + m][n] = __builtin_amdgcn_mfma_f32_16x16x32_bf16(afr[m][0], bfr[n][0], acc[4 + m][n], 0, 0, 0);
        acc[4 + m][n] = __builtin_amdgcn_mfma_f32_16x16x32_bf16(afr[m][1], bfr[n][1], acc[4 + m][n], 0, 0, 0);
      }
    __builtin_amdgcn_s_setprio(0);
    BARRIER();

    // ---- phase 4: quadrant (mh1,nh1); stage A-h1(t+1)
    if (hn) stage16(A, abase, K, ktn, ag0 + 64, As[nb], lane);
    __builtin_amdgcn_s_setprio(1);
#pragma unroll
    for (int m = 0; m < 4; ++m)
#pragma unroll
      for (int n = 0; n < 2; ++n) {
        acc[4 + m][2 + n] = __builtin_amdgcn_mfma_f32_16x16x32_bf16(afr[m][0], bfr[2 + n][0], acc[4 + m][2 + n], 0, 0, 0);
        acc[4 + m][2 + n] = __builtin_amdgcn_mfma_f32_16x16x32_bf16(afr[m][1], bfr[2 + n][1], acc[4 + m][2 + n], 0, 0, 0);
      }
    __builtin_amdgcn_s_setprio(0);
    if (hn) asm volatile("s_waitcnt vmcnt(4)" ::: "memory");
    BARRIER();

    cur ^= 1;
  }

  const int mat = (int)(bbase >> 11);   // block-uniform (2048 % 256 == 0)
  if (Vt != nullptr && mat == 2) {
#pragma unroll
    for (int m = 0; m < 8; ++m)
#pragma unroll
      for (int n = 0; n < 4; ++n)
#pragma unroll
        for (int r = 0; r < 4; ++r) {
          const long row = abase + wr * 128 + m * 16 + orow + r;
          const int col = (int)bbase + wc * 64 + n * 16 + ocol;
          const int e = col & 2047, hh = e >> 7, dd = e & 127;
          const long bb = row >> 11, ss = row & 2047;
          Vt[(((bb << 4) + hh) * 128 + dd) * 2048 + ss] = bf16bits(acc[m][n][r]);
        }
  } else {
#pragma unroll
    for (int m = 0; m < 8; ++m)
#pragma unroll
      for (int n = 0; n < 4; ++n)
#pragma unroll
        for (int r = 0; r < 4; ++r) {
          const long row = abase + wr * 128 + m * 16 + orow + r;
          const int col = (int)bbase + wc * 64 + n * 16 + ocol;
          const float sc = (mat == 0) ? qs : 1.0f;
          const long idx = (long)mat * matStride + row * 2048 + (col & 2047);
          store_out(Cb, idx, acc[m][n][r] * sc);
        }
  }
}

// ---- 128x256 2-phase bf16 GEMM (O-proj: 8x32 = 256 blocks = 1 round) -----

template <typename OUT_T>
__global__ __launch_bounds__(512, 2) void k_gemm2(const u16* __restrict__ A,
                                                  const u16* __restrict__ Bt,
                                                  OUT_T* __restrict__ Cb,
                                                  int M, int N, int K, long matStride,
                                                  float qs) {
  __shared__ u16 As[2][128][64];
  __shared__ u16 Bs[2][256][64];

  const int tid = threadIdx.x, wid = tid >> 6, lane = tid & 63;
  const int wr = wid >> 2, wc = wid & 3;
  const int frow = lane & 15, fk8 = (lane >> 4) * 8;
  const int orow = (lane >> 4) * 4, ocol = lane & 15;

  const int nwg = gridDim.x * gridDim.y;
  const int orig = blockIdx.y * gridDim.x + blockIdx.x;
  const int q = nwg >> 3, rr = nwg & 7;
  const int xcd = orig & 7, sl = orig >> 3;
  const int wg = (xcd < rr ? xcd * (q + 1) : rr * (q + 1) + (xcd - rr) * q) + sl;
  const int by = wg / gridDim.x, bx = wg % gridDim.x;

  const long abase = (long)by * 128, bbase = (long)bx * 256;

  const int bg0 = (wid >> 1) * 64 + (wid & 1) * 16;
  const int ag0 = ((wid & 1) << 6) + ((wid >> 1) << 3);

  f32x4_t acc[4][4];
#pragma unroll
  for (int m = 0; m < 4; ++m)
#pragma unroll
    for (int n = 0; n < 4; ++n)
#pragma unroll
      for (int r = 0; r < 4; ++r) acc[m][n][r] = 0.f;

  const int nt = K >> 6;

  stage16(Bt, bbase, K, 0, bg0, Bs[0], lane);
  stage16(Bt, bbase, K, 0, bg0 + 32, Bs[0], lane);
  stage8 (A,  abase, K, 0, ag0, As[0], lane);
  stage8 (A,  abase, K, 0, ag0 + 32, As[0], lane);
  asm volatile("s_waitcnt vmcnt(1)" ::: "memory");
  BARRIER();

  bf16x8_t bfr[4][2], afr[2][2];
  int cur = 0;

  for (int t = 0; t < nt; ++t) {
    const int ktn = (t + 1) << 6;
    const bool hn = (t + 1 < nt);
    const int nb = cur ^ 1;

#pragma unroll
    for (int n = 0; n < 4; ++n) {
      const int r = wc * 64 + n * 16 + frow;
      bfr[n][0] = *reinterpret_cast<const bf16x8_t*>(&Bs[cur][r][sw8(r, fk8)]);
      bfr[n][1] = *reinterpret_cast<const bf16x8_t*>(&Bs[cur][r][sw8(r, 32 + fk8)]);
    }
#pragma unroll
    for (int m = 0; m < 2; ++m) {
      const int r = wr * 64 + m * 16 + frow;
      afr[m][0] = *reinterpret_cast<const bf16x8_t*>(&As[cur][r][sw8(r, fk8)]);
      afr[m][1] = *reinterpret_cast<const bf16x8_t*>(&As[cur][r][sw8(r, 32 + fk8)]);
    }
    if (hn) {
      stage16(Bt, bbase, K, ktn, bg0, Bs[nb], lane);
      stage16(Bt, bbase, K, ktn, bg0 + 32, Bs[nb], lane);
    }
    BARRIER();
    WAITLGKM();
    __builtin_amdgcn_s_setprio(1);
#pragma unroll
    for (int m = 0; m < 2; ++m)
#pragma unroll
      for (int n = 0; n < 4; ++n) {
        acc[m][n] = __builtin_amdgcn_mfma_f32_16x16x32_bf16(afr[m][0], bfr[n][0], acc[m][n], 0, 0, 0);
        acc[m][n] = __builtin_amdgcn_mfma_f32_16x16x32_bf16(afr[m][1], bfr[n][1], acc[m][n], 0, 0, 0);
      }
    __builtin_amdgcn_s_setprio(0);
    if (hn) asm volatile("s_waitcnt vmcnt(4)" ::: "memory");
    else    asm volatile("s_waitcnt vmcnt(0)" ::: "memory");
    BARRIER();

#pragma unroll
    for (int m = 0; m < 2; ++m) {
      const int r = wr * 64 + 32 + m * 16 + frow;
      afr[m][0] = *reinterpret_cast<const bf16x8_t*>(&As[cur][r][sw8(r, fk8)]);
      afr[m][1] = *reinterpret_cast<const bf16x8_t*>(&As[cur][r][sw8(r, 32 + fk8)]);
    }
    if (hn) {
      stage8(A, abase, K, ktn, ag0, As[nb], lane);
      stage8(A, abase, K, ktn, ag0 + 32, As[nb], lane);
    }
    BARRIER();
    WAITLGKM();
    __builtin_amdgcn_s_setprio(1);
#pragma unroll
    for (int m = 0; m < 2; ++m)
#pragma unroll
      for (int n = 0; n < 4; ++n) {
        acc[2 + m][n] = __builtin_amdgcn_mfma_f32_16x16x32_bf16(afr[m][0], bfr[n][0], acc[2 + m][n], 0, 0, 0);
        acc[2 + m][n] = __builtin_amdgcn_mfma_f32_16x16x32_bf16(afr[m][1], bfr[n][1], acc[2 + m][n], 0, 0, 0);
      }
    __builtin_amdgcn_s_setprio(0);
    if (hn) asm volatile("s_waitcnt vmcnt(1)" ::: "memory");
    BARRIER();

    cur ^= 1;
  }

#pragma unroll
  for (int m = 0; m < 4; ++m)
#pragma unroll
    for (int n = 0; n < 4; ++n)
#pragma unroll
      for (int r = 0; r < 4; ++r) {
        const long row = abase + wr * 64 + m * 16 + orow + r;
        const int col = (int)bbase + wc * 64 + n * 16 + ocol;
        const float sc = ((col >> 11) == 0) ? qs : 1.0f;
        const long idx = (long)(col >> 11) * matStride + row * 2048 + (col & 2047);
        store_out(Cb, idx, acc[m][n][r] * sc);
      }
}

// ---- flash attention, QBLK=128, 4 waves x 32 q-rows (R2 math + R15 pipe) --
// R17: per-wave math/mask verbatim from R2 (passed): 2 m-frags, universal
// global mask kg<=qg applied on tiles kt>=2qb, active = kt*64 <= qg0+31.
// Pipeline verbatim from R15 (passed): descending-k, K/V dbuf, 2 barriers
// per tile (mid: lgkm only), defer-max, log2 domain, bf16bits. Staging is
// R15's 4-wave code. LDS 80KB -> 2 blocks/CU; 512 blocks.

__global__ __launch_bounds__(256) void k_attn(const u16* __restrict__ Q,
                                              const u16* __restrict__ Kb,
                                              const u16* __restrict__ Vt,
                                              u16* __restrict__ Out,
                                              int B, int S, int H, int D,
                                              float log2e) {
  __shared__ u16 Ks[2][64][128];   // 32KB dbuf (swizzled)
  __shared__ u16 Vs[2][128][64];   // 32KB dbuf (swizzled)
  __shared__ u16 Ps[128][64];      // 16KB (wave-private 32-row slabs)

  const int tid = threadIdx.x, wid = tid >> 6, lane = tid & 63;

  const int nq = gridDim.x, nbh = gridDim.y;   // nq = S/128 = 16
  const int lin = blockIdx.x + nq * blockIdx.y;
  const int qb0 = lin / nbh;
  const int bh  = lin % nbh;
  const int qb  = (qb0 < nq / 2) ? qb0 : (nq + nq / 2 - 1 - qb0);

  const int b = bh / H, h = bh % H;
  const int Dh = D / H;

  const float slope2 = alibi_slope(h, H) * log2e;
  const long qrow0 = (long)b * S + qb * 128 + wid * 32;
  const int qg0 = qb * 128 + wid * 32;

  const int frow = lane & 15;
  const int fk8  = (lane >> 4) * 8;
  const int orow = (lane >> 4) * 4;
  const int ocol = lane & 15;

  // Q fragments: 2 m-frags x 4 k-steps (R2 layout; Q prescaled in GEMM)
  bf16x8_t aq[2][4];
#pragma unroll
  for (int m = 0; m < 2; ++m)
#pragma unroll
    for (int kk = 0; kk < 4; ++kk)
      aq[m][kk] = *reinterpret_cast<const bf16x8_t*>(
          Q + (qrow0 + m * 16 + frow) * (long)D + h * Dh + kk * 32 + fk8);

  float cw[4];
#pragma unroll
  for (int n = 0; n < 4; ++n) cw[n] = slope2 * (float)(n * 16 + ocol);

  f32x4_t oacc[2][8];
#pragma unroll
  for (int m = 0; m < 2; ++m)
#pragma unroll
    for (int no = 0; no < 8; ++no)
#pragma unroll
      for (int r = 0; r < 4; ++r) oacc[m][no][r] = 0.f;

  float Mrun[2][4], lrun[2][4];
#pragma unroll
  for (int m = 0; m < 2; ++m)
#pragma unroll
    for (int r = 0; r < 4; ++r) { Mrun[m][r] = -3.0e38f; lrun[m][r] = 0.f; }

  const u16* kbase = Kb + (long)b * S * D + h * Dh;
  const u16* vbase = Vt + (long)bh * Dh * S;

  // R15's 4-wave staging (verbatim)
  auto STAGE = [&](int kt, int bi) {
#pragma unroll
    for (int i = 0; i < 4; ++i) {
      const int lr = i * 16 + wid * 4;
      const int r  = lr + (lane >> 4);
      gload_lds16(kbase + ((long)kt * 64 + r) * (long)D + sw8(r, (lane & 15) * 8),
                  &Ks[bi][lr][0]);
    }
#pragma unroll
    for (int i = 0; i < 4; ++i) {
      const int lr = i * 32 + wid * 8;
      const int r  = lr + (lane >> 3);
      gload_lds16(vbase + (long)r * S + kt * 64 + sw8(r, (lane & 7) * 8),
                  &Vs[bi][lr][0]);
    }
  };

  STAGE(2 * qb + 1, 0);
  asm volatile("s_waitcnt vmcnt(0)" ::: "memory");
  BARRIER();

  int cur = 0;

  for (int kt = 2 * qb + 1; kt >= 0; --kt) {
    if (kt > 0) STAGE(kt - 1, cur ^ 1);

    const bool active = (kt * 64) <= (qg0 + 31);   // R2 condition (32-row wave)

    if (active) {
      f32x4_t sacc[2][4];
#pragma unroll
      for (int m = 0; m < 2; ++m)
#pragma unroll
        for (int n = 0; n < 4; ++n)
#pragma unroll
          for (int r = 0; r < 4; ++r) sacc[m][n][r] = 0.f;

      __builtin_amdgcn_s_setprio(1);
#pragma unroll
      for (int kk = 0; kk < 4; ++kk) {
        bf16x8_t bk[4];
#pragma unroll
        for (int n = 0; n < 4; ++n) {
          const int krow = n * 16 + frow;
          bk[n] = *reinterpret_cast<const bf16x8_t*>(&Ks[cur][krow][sw8(krow, kk * 32 + fk8)]);
        }
#pragma unroll
        for (int m = 0; m < 2; ++m)
#pragma unroll
          for (int n = 0; n < 4; ++n)
            sacc[m][n] = __builtin_amdgcn_mfma_f32_16x16x32_bf16(aq[m][kk], bk[n], sacc[m][n], 0, 0, 0);
      }
      __builtin_amdgcn_s_setprio(0);

      const float tb = slope2 * (float)(kt << 6);
      float cbn[4];
#pragma unroll
      for (int n = 0; n < 4; ++n) cbn[n] = tb + cw[n];

      float tmax[2][4];
#pragma unroll
      for (int m = 0; m < 2; ++m)
#pragma unroll
        for (int r = 0; r < 4; ++r) tmax[m][r] = -3.0e38f;

      if (kt >= 2 * qb) {  // only diagonal-adjacent tiles can be partial (R2 global mask)
#pragma unroll
        for (int m = 0; m < 2; ++m)
#pragma unroll
          for (int n = 0; n < 4; ++n)
#pragma unroll
            for (int r = 0; r < 4; ++r) {
              const int kg = (kt << 6) + n * 16 + ocol;
              const int qg = qg0 + m * 16 + orow + r;
              float v = sacc[m][n][r] + cbn[n];
              v = (kg <= qg) ? v : -1.0e30f;
              sacc[m][n][r] = v;
              tmax[m][r] = fmaxf(tmax[m][r], v);
            }
      } else {
#pragma unroll
        for (int m = 0; m < 2; ++m)
#pragma unroll
          for (int n = 0; n < 4; ++n)
#pragma unroll
            for (int r = 0; r < 4; ++r) {
              const float v = sacc[m][n][r] + cbn[n];
              sacc[m][n][r] = v;
              tmax[m][r] = fmaxf(tmax[m][r], v);
            }
      }
#pragma unroll
      for (int m = 0; m < 2; ++m)
#pragma unroll
        for (int r = 0; r < 4; ++r) {
          float t = tmax[m][r];
          t = fmaxf(t, __shfl_xor(t, 1));
          t = fmaxf(t, __shfl_xor(t, 2));
          t = fmaxf(t, __shfl_xor(t, 4));
          t = fmaxf(t, __shfl_xor(t, 8));
          tmax[m][r] = t;
        }

      // defer-max (T13, THR=11)
      int need = 0;
#pragma unroll
      for (int m = 0; m < 2; ++m)
#pragma unroll
        for (int r = 0; r < 4; ++r) need |= (tmax[m][r] > Mrun[m][r] + 11.0f) ? 1 : 0;
      if (__any(need)) {
#pragma unroll
        for (int m = 0; m < 2; ++m)
#pragma unroll
          for (int r = 0; r < 4; ++r) {
            const float mnew = fmaxf(Mrun[m][r], tmax[m][r]);
            const float alpha = exp2f(Mrun[m][r] - mnew);
            Mrun[m][r] = mnew;
            lrun[m][r] *= alpha;
#pragma unroll
            for (int no = 0; no < 8; ++no) oacc[m][no][r] *= alpha;
          }
      }

      float tsum[2][4];
#pragma unroll
      for (int m = 0; m < 2; ++m)
#pragma unroll
        for (int r = 0; r < 4; ++r) tsum[m][r] = 0.f;
#pragma unroll
      for (int m = 0; m < 2; ++m)
#pragma unroll
        for (int n = 0; n < 4; ++n)
#pragma unroll
          for (int r = 0; r < 4; ++r) {
            const float p = exp2f(sacc[m][n][r] - Mrun[m][r]);
            tsum[m][r] += p;
            const int prow = wid * 32 + m * 16 + orow + r;
            Ps[prow][sw8(prow, n * 16 + ocol)] = bf16bits(p);
          }
#pragma unroll
      for (int m = 0; m < 2; ++m)
#pragma unroll
        for (int r = 0; r < 4; ++r) {
          float t = tsum[m][r];
          t += __shfl_xor(t, 1);
          t += __shfl_xor(t, 2);
          t += __shfl_xor(t, 4);
          t += __shfl_xor(t, 8);
          lrun[m][r] += t;
        }
    }

    WAITLGKM();
    BARRIER();

    if (active) {
      __builtin_amdgcn_s_setprio(1);
#pragma unroll
      for (int kk = 0; kk < 2; ++kk) {
        bf16x8_t pa[2];
        const int prow0 = wid * 32 + frow;
        const int prow1 = wid * 32 + 16 + frow;
        pa[0] = *reinterpret_cast<const bf16x8_t*>(&Ps[prow0][sw8(prow0, kk * 32 + fk8)]);
        pa[1] = *reinterpret_cast<const bf16x8_t*>(&Ps[prow1][sw8(prow1, kk * 32 + fk8)]);
#pragma unroll
        for (int no = 0; no < 8; ++no) {
          const int vrow = no * 16 + frow;
          bf16x8_t bv = *reinterpret_cast<const bf16x8_t*>(&Vs[cur][vrow][sw8(vrow, kk * 32 + fk8)]);
          oacc[0][no] = __builtin_amdgcn_mfma_f32_16x16x32_bf16(pa[0], bv, oacc[0][no], 0, 0, 0);
          oacc[1][no] = __builtin_amdgcn_mfma_f32_16x16x32_bf16(pa[1], bv, oacc[1][no], 0, 0, 0);
        }
      }
      __builtin_amdgcn_s_setprio(0);
    }

    if (kt > 0) {
      asm volatile("s_waitcnt vmcnt(0)" ::: "memory");
      BARRIER();
      cur ^= 1;
    }
  }

#pragma unroll
  for (int m = 0; m < 2; ++m)
#pragma unroll
    for (int r = 0; r < 4; ++r) {
      const float rl = 1.0f / lrun[m][r];
      const long trow = qrow0 + m * 16 + orow + r;
#pragma unroll
      for (int no = 0; no < 8; ++no)
        Out[trow * (long)D + h * Dh + no * 16 + ocol] = bf16bits(oacc[m][no][r] * rl);
    }
}

// ---- launch --------------------------------------------------------------

extern "C" void kernel_launch(void* const* d_in, const int* in_sizes, int n_in,
                              void* d_out, int out_size, void* d_ws, size_t ws_size,
                              hipStream_t stream) {
  const float* hs   = (const float*)d_in[0];
  const float* qkvw = (const float*)d_in[1];
  const float* ow   = (const float*)d_in[2];

  const int D = 2048, B = 2, H = 16;
  const long TD = (long)in_sizes[0];   // T*D = 8388608
  const long DD = (long)in_sizes[2];   // D*D = 4194304
  const int T = (int)(TD / D);         // 4096
  const int S = T / B;                 // 2048
  const int Dh = D / H;                // 128
  const float log2e = 1.44269504f;
  const float qs = (1.0f / sqrtf((float)Dh)) * log2e;  // Q prescale

  u16* ws  = (u16*)d_ws;
  u16* hsb = ws;                  // TD    (later reused as attn)
  u16* wt  = ws + TD;             // 3*DD  (qkv weights^T; +3DD = o-proj^T)
  u16* owt = wt + 3 * DD;         // DD
  u16* qkv = owt + DD;            // 3*TD  [Q | K | Vt]  (Vt fused in GEMM)
  u16* vt   = qkv + 2 * TD;       // Vt[bh][Dh][S] written by QKV epilogue
  u16* attn = hsb;                // TD    (overlay; hsb dead after QKV GEMM)

  // 1) hidden -> bf16
  k_cast_bf16<<<dim3((unsigned)(TD / 1024)), 256, 0, stream>>>(hs, hsb, TD);
  // 2) all weights: cast + transpose in one dispatch (z=0..2: qkvw, z=3: ow)
  k_transpose_cast4<<<dim3(D / 32, D / 32, 4), 256, 0, stream>>>(qkvw, ow, wt, D, D);
  // 3) fused QKV projection + V-transpose epilogue
  k_gemm8<u16><<<dim3((3 * D) / 256, T / 256), 512, 0, stream>>>(
      hsb, wt, qkv, T, 3 * D, D, TD, qs, vt);
  // 4) attention (QBLK=128, 4 waves x 32 rows; R2 math + R15 pipeline)
  k_attn<<<dim3(S / 128, B * H), 256, 0, stream>>>(
      qkv, qkv + TD, vt, attn, B, S, H, D, log2e);
  // 5) output projection -> f32 d_out (128x256 tiles: 256 blocks = 1 round)
  k_gemm2<float><<<dim3(D / 256, T / 128), 512, 0, stream>>>(
      attn, owt, (float*)d_out, T, D, D, 0L, 1.0f);
}

// Round 18
// 291.416 us; speedup vs baseline: 1.0743x; 1.0743x over previous
//
#include <hip/hip_runtime.h>
#include <math.h>
#include <stdint.h>

typedef __bf16 bf16x8_t __attribute__((ext_vector_type(8)));
typedef float  f32x4_t  __attribute__((ext_vector_type(4)));
typedef unsigned short u16;

// ---- helpers -------------------------------------------------------------

__device__ __forceinline__ u16 f2bf(float f) {
  unsigned u = __float_as_uint(f);
  u += 0x7FFFu + ((u >> 16) & 1u);
  return (u16)(u >> 16);
}

// native bf16 convert (RNE)
__device__ __forceinline__ u16 bf16bits(float f) {
  __bf16 b = (__bf16)f;
  return __builtin_bit_cast(u16, b);
}

__device__ __forceinline__ void gload_lds16(const u16* gsrc, u16* ldst) {
  __builtin_amdgcn_global_load_lds(
      (__attribute__((address_space(1))) void*)(const_cast<u16*>(gsrc)),
      (__attribute__((address_space(3))) void*)(ldst),
      16, 0, 0);
}

// XOR swizzle for 128B rows (64 bf16): elem ^= ((row&7)<<3)
__device__ __forceinline__ int sw8(int row, int e) { return e ^ ((row & 7) << 3); }

__device__ __forceinline__ void store_out(float* C, long idx, float v) { C[idx] = v; }
__device__ __forceinline__ void store_out(u16* C, long idx, float v) { C[idx] = f2bf(v); }

__device__ __forceinline__ float alibi_slope(int h, int H) {
  int cp2 = 1, lg = 0;
  while (cp2 * 2 <= H) { cp2 *= 2; lg++; }
  if (h < cp2) {
    double e = exp2((double)-(lg - 3));
    return (float)exp2(-e * (double)(h + 1));
  } else {
    double e = exp2((double)-(lg + 1 - 3));
    return (float)exp2(-e * (double)(2 * (h - cp2) + 1));
  }
}

#define FENCE() asm volatile("" ::: "memory")
#define BARRIER() do { FENCE(); __builtin_amdgcn_s_barrier(); \
                       __builtin_amdgcn_sched_barrier(0); FENCE(); } while (0)
#define WAITLGKM() do { asm volatile("s_waitcnt lgkmcnt(0)" ::: "memory"); \
                        __builtin_amdgcn_sched_barrier(0); } while (0)

// ---- elementwise cast f32 -> bf16 ---------------------------------------

__global__ __launch_bounds__(256) void k_cast_bf16(const float* __restrict__ in,
                                                   u16* __restrict__ out, long n) {
  long i = ((long)blockIdx.x * 256 + threadIdx.x) * 4;
  if (i + 3 < n) {
    float4 v = *reinterpret_cast<const float4*>(in + i);
    ushort4 o;
    o.x = f2bf(v.x); o.y = f2bf(v.y); o.z = f2bf(v.z); o.w = f2bf(v.w);
    *reinterpret_cast<ushort4*>(out + i) = o;
  }
}

// ---- transpose + cast (merged): z<3 -> qkvw[z], z==3 -> ow ----------------

__global__ __launch_bounds__(256) void k_transpose_cast4(const float* __restrict__ in0,
                                                         const float* __restrict__ in1,
                                                         u16* __restrict__ out,
                                                         int R, int C) {
  __shared__ float tile[32][33];
  const float* inz = (blockIdx.z < 3) ? (in0 + (long)blockIdx.z * R * C) : in1;
  u16* outz = out + (long)blockIdx.z * R * C;
  const int tx = threadIdx.x & 31, ty = threadIdx.x >> 5;
  const int r0 = blockIdx.y * 32, c0 = blockIdx.x * 32;
#pragma unroll
  for (int i = 0; i < 4; ++i)
    tile[ty + i * 8][tx] = inz[(long)(r0 + ty + i * 8) * C + c0 + tx];
  __syncthreads();
#pragma unroll
  for (int i = 0; i < 4; ++i)
    outz[(long)(c0 + ty + i * 8) * R + r0 + tx] = f2bf(tile[tx][ty + i * 8]);
}

// ---- staging helpers ------------------------------------------------------

__device__ __forceinline__ void stage16(const u16* __restrict__ g, long grow0, int K,
                                        int kt, int lr0, u16 (*lds)[64], int lane) {
  const int e = (lane & 7) * 8;
#pragma unroll
  for (int i = 0; i < 2; ++i) {
    const int r = lr0 + i * 8 + (lane >> 3);
    gload_lds16(g + (grow0 + r) * (long)K + kt + (e ^ ((r & 7) << 3)), &lds[lr0 + i * 8][0]);
  }
}

__device__ __forceinline__ void stage8(const u16* __restrict__ g, long grow0, int K,
                                       int kt, int lr0, u16 (*lds)[64], int lane) {
  const int e = (lane & 7) * 8;
  const int r = lr0 + (lane >> 3);
  gload_lds16(g + (grow0 + r) * (long)K + kt + (e ^ ((r & 7) << 3)), &lds[lr0][0]);
}

// ---- 256x256 4-phase bf16 GEMM (QKV) + fused V-transpose epilogue --------

template <typename OUT_T>
__global__ __launch_bounds__(512, 2) void k_gemm8(const u16* __restrict__ A,
                                                  const u16* __restrict__ Bt,
                                                  OUT_T* __restrict__ Cb,
                                                  int M, int N, int K, long matStride,
                                                  float qs, u16* __restrict__ Vt) {
  __shared__ u16 As[2][256][64];
  __shared__ u16 Bs[2][256][64];

  const int tid = threadIdx.x, wid = tid >> 6, lane = tid & 63;
  const int wr = wid >> 2, wc = wid & 3;
  const int frow = lane & 15, fk8 = (lane >> 4) * 8;
  const int orow = (lane >> 4) * 4, ocol = lane & 15;

  const int nwg = gridDim.x * gridDim.y;
  const int orig = blockIdx.y * gridDim.x + blockIdx.x;
  const int q = nwg >> 3, rr = nwg & 7;
  const int xcd = orig & 7, sl = orig >> 3;
  const int wg = (xcd < rr ? xcd * (q + 1) : rr * (q + 1) + (xcd - rr) * q) + sl;
  const int by = wg / gridDim.x, bx = wg % gridDim.x;

  const long abase = (long)by * 256, bbase = (long)bx * 256;

  const int bg0 = (wid >> 1) * 64 + (wid & 1) * 16;
  const int ag0 = (wid >> 2) * 128 + (wid & 3) * 16;

  f32x4_t acc[8][4];
#pragma unroll
  for (int m = 0; m < 8; ++m)
#pragma unroll
    for (int n = 0; n < 4; ++n)
#pragma unroll
      for (int r = 0; r < 4; ++r) acc[m][n][r] = 0.f;

  const int nt = K >> 6;

  stage16(A, abase, K, 0, ag0, As[0], lane);
  stage16(Bt, bbase, K, 0, bg0, Bs[0], lane);
  stage16(Bt, bbase, K, 0, bg0 + 32, Bs[0], lane);
  stage16(A, abase, K, 0, ag0 + 64, As[0], lane);
  asm volatile("s_waitcnt vmcnt(4)" ::: "memory");
  BARRIER();

  bf16x8_t afr[4][2], bfr[4][2];
  int cur = 0;

  for (int t = 0; t < nt; ++t) {
    const int ktn = (t + 1) << 6;
    const bool hn = (t + 1 < nt);
    const int nb = cur ^ 1;

    // ---- phase 1
#pragma unroll
    for (int m = 0; m < 4; ++m) {
      const int r = wr * 128 + m * 16 + frow;
      afr[m][0] = *reinterpret_cast<const bf16x8_t*>(&As[cur][r][sw8(r, fk8)]);
      afr[m][1] = *reinterpret_cast<const bf16x8_t*>(&As[cur][r][sw8(r, 32 + fk8)]);
    }
#pragma unroll
    for (int n = 0; n < 2; ++n) {
      const int r = wc * 64 + n * 16 + frow;
      bfr[n][0] = *reinterpret_cast<const bf16x8_t*>(&Bs[cur][r][sw8(r, fk8)]);
      bfr[n][1] = *reinterpret_cast<const bf16x8_t*>(&Bs[cur][r][sw8(r, 32 + fk8)]);
    }
    if (hn) stage16(A, abase, K, ktn, ag0, As[nb], lane);
    BARRIER();
    WAITLGKM();
    __builtin_amdgcn_s_setprio(1);
#pragma unroll
    for (int m = 0; m < 4; ++m)
#pragma unroll
      for (int n = 0; n < 2; ++n) {
        acc[m][n] = __builtin_amdgcn_mfma_f32_16x16x32_bf16(afr[m][0], bfr[n][0], acc[m][n], 0, 0, 0);
        acc[m][n] = __builtin_amdgcn_mfma_f32_16x16x32_bf16(afr[m][1], bfr[n][1], acc[m][n], 0, 0, 0);
      }
    __builtin_amdgcn_s_setprio(0);
    if (hn) asm volatile("s_waitcnt vmcnt(4)" ::: "memory");
    else    asm volatile("s_waitcnt vmcnt(2)" ::: "memory");
    BARRIER();

    // ---- phase 2
#pragma unroll
    for (int n = 0; n < 2; ++n) {
      const int r = wc * 64 + 32 + n * 16 + frow;
      bfr[2 + n][0] = *reinterpret_cast<const bf16x8_t*>(&Bs[cur][r][sw8(r, fk8)]);
      bfr[2 + n][1] = *reinterpret_cast<const bf16x8_t*>(&Bs[cur][r][sw8(r, 32 + fk8)]);
    }
    if (hn) stage16(Bt, bbase, K, ktn, bg0, Bs[nb], lane);
    BARRIER();
    WAITLGKM();
    __builtin_amdgcn_s_setprio(1);
#pragma unroll
    for (int m = 0; m < 4; ++m)
#pragma unroll
      for (int n = 0; n < 2; ++n) {
        acc[m][2 + n] = __builtin_amdgcn_mfma_f32_16x16x32_bf16(afr[m][0], bfr[2 + n][0], acc[m][2 + n], 0, 0, 0);
        acc[m][2 + n] = __builtin_amdgcn_mfma_f32_16x16x32_bf16(afr[m][1], bfr[2 + n][1], acc[m][2 + n], 0, 0, 0);
      }
    __builtin_amdgcn_s_setprio(0);
    if (!hn) asm volatile("s_waitcnt vmcnt(0)" ::: "memory");
    BARRIER();

    // ---- phase 3
#pragma unroll
    for (int m = 0; m < 4; ++m) {
      const int r = wr * 128 + 64 + m * 16 + frow;
      afr[m][0] = *reinterpret_cast<const bf16x8_t*>(&As[cur][r][sw8(r, fk8)]);
      afr[m][1] = *reinterpret_cast<const bf16x8_t*>(&As[cur][r][sw8(r, 32 + fk8)]);
    }
    if (hn) stage16(Bt, bbase, K, ktn, bg0 + 32, Bs[nb], lane);
    BARRIER();
    WAITLGKM();
    __builtin_amdgcn_s_setprio(1);
#pragma unroll
    for (int m = 0; m < 4; ++m)
#pragma unroll
      for (int n = 0; n < 2; ++n) {
        acc[4 + m][n] = __builtin_amdgcn_mfma_f32_16x16x32_bf16(afr[m][0], bfr[n][0], acc[4 + m][n], 0, 0, 0);
        acc[4 + m][n] = __builtin_amdgcn_mfma_f32_16x16x32_bf16(afr[m][1], bfr[n][1], acc[4 + m][n], 0, 0, 0);
      }
    __builtin_amdgcn_s_setprio(0);
    BARRIER();

    // ---- phase 4
    if (hn) stage16(A, abase, K, ktn, ag0 + 64, As[nb], lane);
    __builtin_amdgcn_s_setprio(1);
#pragma unroll
    for (int m = 0; m < 4; ++m)
#pragma unroll
      for (int n = 0; n < 2; ++n) {
        acc[4 + m][2 + n] = __builtin_amdgcn_mfma_f32_16x16x32_bf16(afr[m][0], bfr[2 + n][0], acc[4 + m][2 + n], 0, 0, 0);
        acc[4 + m][2 + n] = __builtin_amdgcn_mfma_f32_16x16x32_bf16(afr[m][1], bfr[2 + n][1], acc[4 + m][2 + n], 0, 0, 0);
      }
    __builtin_amdgcn_s_setprio(0);
    if (hn) asm volatile("s_waitcnt vmcnt(4)" ::: "memory");
    BARRIER();

    cur ^= 1;
  }

  const int mat = (int)(bbase >> 11);
  if (Vt != nullptr && mat == 2) {
#pragma unroll
    for (int m = 0; m < 8; ++m)
#pragma unroll
      for (int n = 0; n < 4; ++n)
#pragma unroll
        for (int r = 0; r < 4; ++r) {
          const long row = abase + wr * 128 + m * 16 + orow + r;
          const int col = (int)bbase + wc * 64 + n * 16 + ocol;
          const int e = col & 2047, hh = e >> 7, dd = e & 127;
          const long bb = row >> 11, ss = row & 2047;
          Vt[(((bb << 4) + hh) * 128 + dd) * 2048 + ss] = bf16bits(acc[m][n][r]);
        }
  } else {
#pragma unroll
    for (int m = 0; m < 8; ++m)
#pragma unroll
      for (int n = 0; n < 4; ++n)
#pragma unroll
        for (int r = 0; r < 4; ++r) {
          const long row = abase + wr * 128 + m * 16 + orow + r;
          const int col = (int)bbase + wc * 64 + n * 16 + ocol;
          const float sc = (mat == 0) ? qs : 1.0f;
          const long idx = (long)mat * matStride + row * 2048 + (col & 2047);
          store_out(Cb, idx, acc[m][n][r] * sc);
        }
  }
}

// ---- 128x256 2-phase bf16 GEMM (O-proj) -----------------------------------

template <typename OUT_T>
__global__ __launch_bounds__(512, 2) void k_gemm2(const u16* __restrict__ A,
                                                  const u16* __restrict__ Bt,
                                                  OUT_T* __restrict__ Cb,
                                                  int M, int N, int K, long matStride,
                                                  float qs) {
  __shared__ u16 As[2][128][64];
  __shared__ u16 Bs[2][256][64];

  const int tid = threadIdx.x, wid = tid >> 6, lane = tid & 63;
  const int wr = wid >> 2, wc = wid & 3;
  const int frow = lane & 15, fk8 = (lane >> 4) * 8;
  const int orow = (lane >> 4) * 4, ocol = lane & 15;

  const int nwg = gridDim.x * gridDim.y;
  const int orig = blockIdx.y * gridDim.x + blockIdx.x;
  const int q = nwg >> 3, rr = nwg & 7;
  const int xcd = orig & 7, sl = orig >> 3;
  const int wg = (xcd < rr ? xcd * (q + 1) : rr * (q + 1) + (xcd - rr) * q) + sl;
  const int by = wg / gridDim.x, bx = wg % gridDim.x;

  const long abase = (long)by * 128, bbase = (long)bx * 256;

  const int bg0 = (wid >> 1) * 64 + (wid & 1) * 16;
  const int ag0 = ((wid & 1) << 6) + ((wid >> 1) << 3);

  f32x4_t acc[4][4];
#pragma unroll
  for (int m = 0; m < 4; ++m)
#pragma unroll
    for (int n = 0; n < 4; ++n)
#pragma unroll
      for (int r = 0; r < 4; ++r) acc[m][n][r] = 0.f;

  const int nt = K >> 6;

  stage16(Bt, bbase, K, 0, bg0, Bs[0], lane);
  stage16(Bt, bbase, K, 0, bg0 + 32, Bs[0], lane);
  stage8 (A,  abase, K, 0, ag0, As[0], lane);
  stage8 (A,  abase, K, 0, ag0 + 32, As[0], lane);
  asm volatile("s_waitcnt vmcnt(1)" ::: "memory");
  BARRIER();

  bf16x8_t bfr[4][2], afr[2][2];
  int cur = 0;

  for (int t = 0; t < nt; ++t) {
    const int ktn = (t + 1) << 6;
    const bool hn = (t + 1 < nt);
    const int nb = cur ^ 1;

#pragma unroll
    for (int n = 0; n < 4; ++n) {
      const int r = wc * 64 + n * 16 + frow;
      bfr[n][0] = *reinterpret_cast<const bf16x8_t*>(&Bs[cur][r][sw8(r, fk8)]);
      bfr[n][1] = *reinterpret_cast<const bf16x8_t*>(&Bs[cur][r][sw8(r, 32 + fk8)]);
    }
#pragma unroll
    for (int m = 0; m < 2; ++m) {
      const int r = wr * 64 + m * 16 + frow;
      afr[m][0] = *reinterpret_cast<const bf16x8_t*>(&As[cur][r][sw8(r, fk8)]);
      afr[m][1] = *reinterpret_cast<const bf16x8_t*>(&As[cur][r][sw8(r, 32 + fk8)]);
    }
    if (hn) {
      stage16(Bt, bbase, K, ktn, bg0, Bs[nb], lane);
      stage16(Bt, bbase, K, ktn, bg0 + 32, Bs[nb], lane);
    }
    BARRIER();
    WAITLGKM();
    __builtin_amdgcn_s_setprio(1);
#pragma unroll
    for (int m = 0; m < 2; ++m)
#pragma unroll
      for (int n = 0; n < 4; ++n) {
        acc[m][n] = __builtin_amdgcn_mfma_f32_16x16x32_bf16(afr[m][0], bfr[n][0], acc[m][n], 0, 0, 0);
        acc[m][n] = __builtin_amdgcn_mfma_f32_16x16x32_bf16(afr[m][1], bfr[n][1], acc[m][n], 0, 0, 0);
      }
    __builtin_amdgcn_s_setprio(0);
    if (hn) asm volatile("s_waitcnt vmcnt(4)" ::: "memory");
    else    asm volatile("s_waitcnt vmcnt(0)" ::: "memory");
    BARRIER();

#pragma unroll
    for (int m = 0; m < 2; ++m) {
      const int r = wr * 64 + 32 + m * 16 + frow;
      afr[m][0] = *reinterpret_cast<const bf16x8_t*>(&As[cur][r][sw8(r, fk8)]);
      afr[m][1] = *reinterpret_cast<const bf16x8_t*>(&As[cur][r][sw8(r, 32 + fk8)]);
    }
    if (hn) {
      stage8(A, abase, K, ktn, ag0, As[nb], lane);
      stage8(A, abase, K, ktn, ag0 + 32, As[nb], lane);
    }
    BARRIER();
    WAITLGKM();
    __builtin_amdgcn_s_setprio(1);
#pragma unroll
    for (int m = 0; m < 2; ++m)
#pragma unroll
      for (int n = 0; n < 4; ++n) {
        acc[2 + m][n] = __builtin_amdgcn_mfma_f32_16x16x32_bf16(afr[m][0], bfr[n][0], acc[2 + m][n], 0, 0, 0);
        acc[2 + m][n] = __builtin_amdgcn_mfma_f32_16x16x32_bf16(afr[m][1], bfr[n][1], acc[2 + m][n], 0, 0, 0);
      }
    __builtin_amdgcn_s_setprio(0);
    if (hn) asm volatile("s_waitcnt vmcnt(1)" ::: "memory");
    BARRIER();

    cur ^= 1;
  }

#pragma unroll
  for (int m = 0; m < 4; ++m)
#pragma unroll
    for (int n = 0; n < 4; ++n)
#pragma unroll
      for (int r = 0; r < 4; ++r) {
        const long row = abase + wr * 64 + m * 16 + orow + r;
        const int col = (int)bbase + wc * 64 + n * 16 + ocol;
        const float sc = ((col >> 11) == 0) ? qs : 1.0f;
        const long idx = (long)(col >> 11) * matStride + row * 2048 + (col & 2047);
        store_out(Cb, idx, acc[m][n][r] * sc);
      }
}

// ---- flash attention, two-strip balanced (R15 body x 2 strips) ------------
// R18: grid (S/128, B*H) = (16, 32) = 512 blocks; each block processes TWO
// QBLK=64 strips: qb = bx and 31-bx -> (qb+1)+(32-qb) = 33 tiles/block,
// exactly constant -> perfect balance at 2 blocks/CU, 1 round. Strip body
// is R15's passing kernel verbatim (descending-k, K/V dbuf, defer-max,
// log2 domain). Barrier between strips protects LDS reuse.

__global__ __launch_bounds__(256) void k_attn(const u16* __restrict__ Q,
                                              const u16* __restrict__ Kb,
                                              const u16* __restrict__ Vt,
                                              u16* __restrict__ Out,
                                              int B, int S, int H, int D,
                                              float log2e) {
  __shared__ u16 Ks[2][64][128];   // 32KB dbuf (swizzled)
  __shared__ u16 Vs[2][128][64];   // 32KB dbuf (swizzled)
  __shared__ u16 Ps[64][64];       //  8KB

  const int tid = threadIdx.x, wid = tid >> 6, lane = tid & 63;

  const int nstrips = 2 * gridDim.x;           // 32
  const int bh = blockIdx.y;
  const int b = bh / H, h = bh % H;
  const int Dh = D / H;

  const float slope2 = alibi_slope(h, H) * log2e;

  const int frow = lane & 15;
  const int fk8  = (lane >> 4) * 8;
  const int orow = (lane >> 4) * 4;
  const int ocol = lane & 15;

  float cw[4];
#pragma unroll
  for (int n = 0; n < 4; ++n) cw[n] = slope2 * (float)(n * 16 + ocol);

  const u16* kbase = Kb + (long)b * S * D + h * Dh;
  const u16* vbase = Vt + (long)bh * Dh * S;

  auto STAGE = [&](int kt, int bi) {
#pragma unroll
    for (int i = 0; i < 4; ++i) {
      const int lr = i * 16 + wid * 4;
      const int r  = lr + (lane >> 4);
      gload_lds16(kbase + ((long)kt * 64 + r) * (long)D + sw8(r, (lane & 15) * 8),
                  &Ks[bi][lr][0]);
    }
#pragma unroll
    for (int i = 0; i < 4; ++i) {
      const int lr = i * 32 + wid * 8;
      const int r  = lr + (lane >> 3);
      gload_lds16(vbase + (long)r * S + kt * 64 + sw8(r, (lane & 7) * 8),
                  &Vs[bi][lr][0]);
    }
  };

  for (int strip = 0; strip < 2; ++strip) {
    const int qb = strip ? (nstrips - 1 - blockIdx.x) : blockIdx.x;

    const long qrow0 = (long)b * S + qb * 64 + wid * 16;
    const int qg0 = qb * 64 + wid * 16;

    bf16x8_t aq[4];
#pragma unroll
    for (int kk = 0; kk < 4; ++kk)
      aq[kk] = *reinterpret_cast<const bf16x8_t*>(
          Q + (qrow0 + frow) * (long)D + h * Dh + kk * 32 + fk8);

    f32x4_t oacc[8];
#pragma unroll
    for (int no = 0; no < 8; ++no)
#pragma unroll
      for (int r = 0; r < 4; ++r) oacc[no][r] = 0.f;

    float Mrun[4], lrun[4];
#pragma unroll
    for (int r = 0; r < 4; ++r) { Mrun[r] = -3.0e38f; lrun[r] = 0.f; }

    // prologue: stage the (diagonal) first tile
    STAGE(qb, 0);
    asm volatile("s_waitcnt vmcnt(0)" ::: "memory");
    BARRIER();

    int cur = 0;

    for (int kt = qb; kt >= 0; --kt) {
      if (kt > 0) STAGE(kt - 1, cur ^ 1);

      f32x4_t sacc[4];
#pragma unroll
      for (int n = 0; n < 4; ++n)
#pragma unroll
        for (int r = 0; r < 4; ++r) sacc[n][r] = 0.f;

      __builtin_amdgcn_s_setprio(1);
#pragma unroll
      for (int kk = 0; kk < 4; ++kk) {
        bf16x8_t bk[4];
#pragma unroll
        for (int n = 0; n < 4; ++n) {
          const int krow = n * 16 + frow;
          bk[n] = *reinterpret_cast<const bf16x8_t*>(&Ks[cur][krow][sw8(krow, kk * 32 + fk8)]);
        }
#pragma unroll
        for (int n = 0; n < 4; ++n)
          sacc[n] = __builtin_amdgcn_mfma_f32_16x16x32_bf16(aq[kk], bk[n], sacc[n], 0, 0, 0);
      }
      __builtin_amdgcn_s_setprio(0);

      const float tb = slope2 * (float)(kt << 6);
      float cbn[4];
#pragma unroll
      for (int n = 0; n < 4; ++n) cbn[n] = tb + cw[n];

      float tmax[4];
#pragma unroll
      for (int r = 0; r < 4; ++r) tmax[r] = -3.0e38f;

      if (kt == qb) {
#pragma unroll
        for (int n = 0; n < 4; ++n)
#pragma unroll
          for (int r = 0; r < 4; ++r) {
            float v = sacc[n][r] + cbn[n];
            v = (n * 16 + ocol <= wid * 16 + orow + r) ? v : -1.0e30f;
            sacc[n][r] = v;
            tmax[r] = fmaxf(tmax[r], v);
          }
      } else {
#pragma unroll
        for (int n = 0; n < 4; ++n)
#pragma unroll
          for (int r = 0; r < 4; ++r) {
            const float v = sacc[n][r] + cbn[n];
            sacc[n][r] = v;
            tmax[r] = fmaxf(tmax[r], v);
          }
      }
#pragma unroll
      for (int r = 0; r < 4; ++r) {
        float t = tmax[r];
        t = fmaxf(t, __shfl_xor(t, 1));
        t = fmaxf(t, __shfl_xor(t, 2));
        t = fmaxf(t, __shfl_xor(t, 4));
        t = fmaxf(t, __shfl_xor(t, 8));
        tmax[r] = t;
      }

      int need = 0;
#pragma unroll
      for (int r = 0; r < 4; ++r) need |= (tmax[r] > Mrun[r] + 11.0f) ? 1 : 0;
      if (__any(need)) {
#pragma unroll
        for (int r = 0; r < 4; ++r) {
          const float mnew = fmaxf(Mrun[r], tmax[r]);
          const float alpha = exp2f(Mrun[r] - mnew);
          Mrun[r] = mnew;
          lrun[r] *= alpha;
#pragma unroll
          for (int no = 0; no < 8; ++no) oacc[no][r] *= alpha;
        }
      }

      float tsum[4];
#pragma unroll
      for (int r = 0; r < 4; ++r) tsum[r] = 0.f;
#pragma unroll
      for (int n = 0; n < 4; ++n)
#pragma unroll
        for (int r = 0; r < 4; ++r) {
          const float p = exp2f(sacc[n][r] - Mrun[r]);
          tsum[r] += p;
          const int prow = wid * 16 + orow + r;
          Ps[prow][sw8(prow, n * 16 + ocol)] = bf16bits(p);
        }
#pragma unroll
      for (int r = 0; r < 4; ++r) {
        float t = tsum[r];
        t += __shfl_xor(t, 1);
        t += __shfl_xor(t, 2);
        t += __shfl_xor(t, 4);
        t += __shfl_xor(t, 8);
        lrun[r] += t;
      }

      WAITLGKM();
      BARRIER();

      __builtin_amdgcn_s_setprio(1);
#pragma unroll
      for (int kk = 0; kk < 2; ++kk) {
        const int prow = wid * 16 + frow;
        bf16x8_t pa = *reinterpret_cast<const bf16x8_t*>(&Ps[prow][sw8(prow, kk * 32 + fk8)]);
#pragma unroll
        for (int no = 0; no < 8; ++no) {
          const int vrow = no * 16 + frow;
          bf16x8_t bv = *reinterpret_cast<const bf16x8_t*>(&Vs[cur][vrow][sw8(vrow, kk * 32 + fk8)]);
          oacc[no] = __builtin_amdgcn_mfma_f32_16x16x32_bf16(pa, bv, oacc[no], 0, 0, 0);
        }
      }
      __builtin_amdgcn_s_setprio(0);

      if (kt > 0) {
        asm volatile("s_waitcnt vmcnt(0)" ::: "memory");
        BARRIER();
        cur ^= 1;
      }
    }

    // epilogue for this strip
#pragma unroll
    for (int r = 0; r < 4; ++r) {
      const float rl = 1.0f / lrun[r];
      const long trow = qrow0 + orow + r;
#pragma unroll
      for (int no = 0; no < 8; ++no)
        Out[trow * (long)D + h * Dh + no * 16 + ocol] = bf16bits(oacc[no][r] * rl);
    }

    // all waves done reading this strip's LDS before next strip's STAGE
    if (strip == 0) BARRIER();
  }
}

// ---- launch --------------------------------------------------------------

extern "C" void kernel_launch(void* const* d_in, const int* in_sizes, int n_in,
                              void* d_out, int out_size, void* d_ws, size_t ws_size,
                              hipStream_t stream) {
  const float* hs   = (const float*)d_in[0];
  const float* qkvw = (const float*)d_in[1];
  const float* ow   = (const float*)d_in[2];

  const int D = 2048, B = 2, H = 16;
  const long TD = (long)in_sizes[0];   // T*D = 8388608
  const long DD = (long)in_sizes[2];   // D*D = 4194304
  const int T = (int)(TD / D);         // 4096
  const int S = T / B;                 // 2048
  const int Dh = D / H;                // 128
  const float log2e = 1.44269504f;
  const float qs = (1.0f / sqrtf((float)Dh)) * log2e;  // Q prescale

  u16* ws  = (u16*)d_ws;
  u16* hsb = ws;                  // TD    (later reused as attn)
  u16* wt  = ws + TD;             // 3*DD  (qkv weights^T; +3DD = o-proj^T)
  u16* owt = wt + 3 * DD;         // DD
  u16* qkv = owt + DD;            // 3*TD  [Q | K | Vt]  (Vt fused in GEMM)
  u16* vt   = qkv + 2 * TD;       // Vt[bh][Dh][S] written by QKV epilogue
  u16* attn = hsb;                // TD    (overlay; hsb dead after QKV GEMM)

  // 1) hidden -> bf16
  k_cast_bf16<<<dim3((unsigned)(TD / 1024)), 256, 0, stream>>>(hs, hsb, TD);
  // 2) all weights: cast + transpose in one dispatch
  k_transpose_cast4<<<dim3(D / 32, D / 32, 4), 256, 0, stream>>>(qkvw, ow, wt, D, D);
  // 3) fused QKV projection + V-transpose epilogue
  k_gemm8<u16><<<dim3((3 * D) / 256, T / 256), 512, 0, stream>>>(
      hsb, wt, qkv, T, 3 * D, D, TD, qs, vt);
  // 4) attention (two balanced QBLK=64 strips per block: 33 tiles constant)
  k_attn<<<dim3(S / 128, B * H), 256, 0, stream>>>(
      qkv, qkv + TD, vt, attn, B, S, H, D, log2e);
  // 5) output projection -> f32 d_out
  k_gemm2<float><<<dim3(D / 256, T / 128), 512, 0, stream>>>(
      attn, owt, (float*)d_out, T, D, D, 0L, 1.0f);
}

// Round 19
// 283.115 us; speedup vs baseline: 1.1058x; 1.0293x over previous
//
#include <hip/hip_runtime.h>
#include <math.h>
#include <stdint.h>

typedef __bf16 bf16x8_t __attribute__((ext_vector_type(8)));
typedef float  f32x4_t  __attribute__((ext_vector_type(4)));
typedef unsigned short u16;

// ---- helpers -------------------------------------------------------------

__device__ __forceinline__ u16 f2bf(float f) {
  unsigned u = __float_as_uint(f);
  u += 0x7FFFu + ((u >> 16) & 1u);
  return (u16)(u >> 16);
}

// native bf16 convert (RNE) — 1 VALU op vs f2bf's 3
__device__ __forceinline__ u16 bf16bits(float f) {
  __bf16 b = (__bf16)f;
  return __builtin_bit_cast(u16, b);
}

__device__ __forceinline__ void gload_lds16(const u16* gsrc, u16* ldst) {
  // async global->LDS, 16B per lane; LDS dest = wave-uniform base + lane*16
  __builtin_amdgcn_global_load_lds(
      (__attribute__((address_space(1))) void*)(const_cast<u16*>(gsrc)),
      (__attribute__((address_space(3))) void*)(ldst),
      16, 0, 0);
}

// XOR swizzle for 128B rows (64 bf16): byte ^= ((row&7)<<4) == elem ^= ((row&7)<<3)
__device__ __forceinline__ int sw8(int row, int e) { return e ^ ((row & 7) << 3); }

__device__ __forceinline__ void store_out(float* C, long idx, float v) { C[idx] = v; }
__device__ __forceinline__ void store_out(u16* C, long idx, float v) { C[idx] = f2bf(v); }

__device__ __forceinline__ float alibi_slope(int h, int H) {
  int cp2 = 1, lg = 0;
  while (cp2 * 2 <= H) { cp2 *= 2; lg++; }
  if (h < cp2) {
    double e = exp2((double)-(lg - 3));
    return (float)exp2(-e * (double)(h + 1));
  } else {
    double e = exp2((double)-(lg + 1 - 3));
    return (float)exp2(-e * (double)(2 * (h - cp2) + 1));
  }
}

#define FENCE() asm volatile("" ::: "memory")
#define BARRIER() do { FENCE(); __builtin_amdgcn_s_barrier(); \
                       __builtin_amdgcn_sched_barrier(0); FENCE(); } while (0)
#define WAITLGKM() do { asm volatile("s_waitcnt lgkmcnt(0)" ::: "memory"); \
                        __builtin_amdgcn_sched_barrier(0); } while (0)

// ---- elementwise cast f32 -> bf16 ---------------------------------------

__global__ __launch_bounds__(256) void k_cast_bf16(const float* __restrict__ in,
                                                   u16* __restrict__ out, long n) {
  long i = ((long)blockIdx.x * 256 + threadIdx.x) * 4;
  if (i + 3 < n) {
    float4 v = *reinterpret_cast<const float4*>(in + i);
    ushort4 o;
    o.x = f2bf(v.x); o.y = f2bf(v.y); o.z = f2bf(v.z); o.w = f2bf(v.w);
    *reinterpret_cast<ushort4*>(out + i) = o;
  }
}

// ---- transpose + cast (merged): z<3 -> qkvw[z], z==3 -> ow ----------------

__global__ __launch_bounds__(256) void k_transpose_cast4(const float* __restrict__ in0,
                                                         const float* __restrict__ in1,
                                                         u16* __restrict__ out,
                                                         int R, int C) {
  __shared__ float tile[32][33];
  const float* inz = (blockIdx.z < 3) ? (in0 + (long)blockIdx.z * R * C) : in1;
  u16* outz = out + (long)blockIdx.z * R * C;
  const int tx = threadIdx.x & 31, ty = threadIdx.x >> 5;
  const int r0 = blockIdx.y * 32, c0 = blockIdx.x * 32;
#pragma unroll
  for (int i = 0; i < 4; ++i)
    tile[ty + i * 8][tx] = inz[(long)(r0 + ty + i * 8) * C + c0 + tx];
  __syncthreads();
#pragma unroll
  for (int i = 0; i < 4; ++i)
    outz[(long)(c0 + ty + i * 8) * R + r0 + tx] = f2bf(tile[tx][ty + i * 8]);
}

// ---- staging helpers (linear LDS dest + inverse-swizzled global source) --

__device__ __forceinline__ void stage16(const u16* __restrict__ g, long grow0, int K,
                                        int kt, int lr0, u16 (*lds)[64], int lane) {
  const int e = (lane & 7) * 8;
#pragma unroll
  for (int i = 0; i < 2; ++i) {
    const int r = lr0 + i * 8 + (lane >> 3);
    gload_lds16(g + (grow0 + r) * (long)K + kt + (e ^ ((r & 7) << 3)), &lds[lr0 + i * 8][0]);
  }
}

__device__ __forceinline__ void stage8(const u16* __restrict__ g, long grow0, int K,
                                       int kt, int lr0, u16 (*lds)[64], int lane) {
  const int e = (lane & 7) * 8;
  const int r = lr0 + (lane >> 3);
  gload_lds16(g + (grow0 + r) * (long)K + kt + (e ^ ((r & 7) << 3)), &lds[lr0][0]);
}

// ---- 256x256 4-phase bf16 GEMM (QKV) + fused V-transpose epilogue --------

template <typename OUT_T>
__global__ __launch_bounds__(512, 2) void k_gemm8(const u16* __restrict__ A,
                                                  const u16* __restrict__ Bt,
                                                  OUT_T* __restrict__ Cb,
                                                  int M, int N, int K, long matStride,
                                                  float qs, u16* __restrict__ Vt) {
  __shared__ u16 As[2][256][64];
  __shared__ u16 Bs[2][256][64];

  const int tid = threadIdx.x, wid = tid >> 6, lane = tid & 63;
  const int wr = wid >> 2, wc = wid & 3;
  const int frow = lane & 15, fk8 = (lane >> 4) * 8;
  const int orow = (lane >> 4) * 4, ocol = lane & 15;

  const int nwg = gridDim.x * gridDim.y;
  const int orig = blockIdx.y * gridDim.x + blockIdx.x;
  const int q = nwg >> 3, rr = nwg & 7;
  const int xcd = orig & 7, sl = orig >> 3;
  const int wg = (xcd < rr ? xcd * (q + 1) : rr * (q + 1) + (xcd - rr) * q) + sl;
  const int by = wg / gridDim.x, bx = wg % gridDim.x;

  const long abase = (long)by * 256, bbase = (long)bx * 256;

  const int bg0 = (wid >> 1) * 64 + (wid & 1) * 16;
  const int ag0 = (wid >> 2) * 128 + (wid & 3) * 16;

  f32x4_t acc[8][4];
#pragma unroll
  for (int m = 0; m < 8; ++m)
#pragma unroll
    for (int n = 0; n < 4; ++n)
#pragma unroll
      for (int r = 0; r < 4; ++r) acc[m][n][r] = 0.f;

  const int nt = K >> 6;

  stage16(A, abase, K, 0, ag0, As[0], lane);
  stage16(Bt, bbase, K, 0, bg0, Bs[0], lane);
  stage16(Bt, bbase, K, 0, bg0 + 32, Bs[0], lane);
  stage16(A, abase, K, 0, ag0 + 64, As[0], lane);
  asm volatile("s_waitcnt vmcnt(4)" ::: "memory");
  BARRIER();

  bf16x8_t afr[4][2], bfr[4][2];
  int cur = 0;

  for (int t = 0; t < nt; ++t) {
    const int ktn = (t + 1) << 6;
    const bool hn = (t + 1 < nt);
    const int nb = cur ^ 1;

    // ---- phase 1: quadrant (mh0,nh0); stage A-h0(t+1)
#pragma unroll
    for (int m = 0; m < 4; ++m) {
      const int r = wr * 128 + m * 16 + frow;
      afr[m][0] = *reinterpret_cast<const bf16x8_t*>(&As[cur][r][sw8(r, fk8)]);
      afr[m][1] = *reinterpret_cast<const bf16x8_t*>(&As[cur][r][sw8(r, 32 + fk8)]);
    }
#pragma unroll
    for (int n = 0; n < 2; ++n) {
      const int r = wc * 64 + n * 16 + frow;
      bfr[n][0] = *reinterpret_cast<const bf16x8_t*>(&Bs[cur][r][sw8(r, fk8)]);
      bfr[n][1] = *reinterpret_cast<const bf16x8_t*>(&Bs[cur][r][sw8(r, 32 + fk8)]);
    }
    if (hn) stage16(A, abase, K, ktn, ag0, As[nb], lane);
    BARRIER();
    WAITLGKM();
    __builtin_amdgcn_s_setprio(1);
#pragma unroll
    for (int m = 0; m < 4; ++m)
#pragma unroll
      for (int n = 0; n < 2; ++n) {
        acc[m][n] = __builtin_amdgcn_mfma_f32_16x16x32_bf16(afr[m][0], bfr[n][0], acc[m][n], 0, 0, 0);
        acc[m][n] = __builtin_amdgcn_mfma_f32_16x16x32_bf16(afr[m][1], bfr[n][1], acc[m][n], 0, 0, 0);
      }
    __builtin_amdgcn_s_setprio(0);
    if (hn) asm volatile("s_waitcnt vmcnt(4)" ::: "memory");
    else    asm volatile("s_waitcnt vmcnt(2)" ::: "memory");
    BARRIER();

    // ---- phase 2: quadrant (mh0,nh1); stage B-h0(t+1)
#pragma unroll
    for (int n = 0; n < 2; ++n) {
      const int r = wc * 64 + 32 + n * 16 + frow;
      bfr[2 + n][0] = *reinterpret_cast<const bf16x8_t*>(&Bs[cur][r][sw8(r, fk8)]);
      bfr[2 + n][1] = *reinterpret_cast<const bf16x8_t*>(&Bs[cur][r][sw8(r, 32 + fk8)]);
    }
    if (hn) stage16(Bt, bbase, K, ktn, bg0, Bs[nb], lane);
    BARRIER();
    WAITLGKM();
    __builtin_amdgcn_s_setprio(1);
#pragma unroll
    for (int m = 0; m < 4; ++m)
#pragma unroll
      for (int n = 0; n < 2; ++n) {
        acc[m][2 + n] = __builtin_amdgcn_mfma_f32_16x16x32_bf16(afr[m][0], bfr[2 + n][0], acc[m][2 + n], 0, 0, 0);
        acc[m][2 + n] = __builtin_amdgcn_mfma_f32_16x16x32_bf16(afr[m][1], bfr[2 + n][1], acc[m][2 + n], 0, 0, 0);
      }
    __builtin_amdgcn_s_setprio(0);
    if (!hn) asm volatile("s_waitcnt vmcnt(0)" ::: "memory");
    BARRIER();

    // ---- phase 3: quadrant (mh1,nh0); stage B-h1(t+1)
#pragma unroll
    for (int m = 0; m < 4; ++m) {
      const int r = wr * 128 + 64 + m * 16 + frow;
      afr[m][0] = *reinterpret_cast<const bf16x8_t*>(&As[cur][r][sw8(r, fk8)]);
      afr[m][1] = *reinterpret_cast<const bf16x8_t*>(&As[cur][r][sw8(r, 32 + fk8)]);
    }
    if (hn) stage16(Bt, bbase, K, ktn, bg0 + 32, Bs[nb], lane);
    BARRIER();
    WAITLGKM();
    __builtin_amdgcn_s_setprio(1);
#pragma unroll
    for (int m = 0; m < 4; ++m)
#pragma unroll
      for (int n = 0; n < 2; ++n) {
        acc[4 + m][n] = __builtin_amdgcn_mfma_f32_16x16x32_bf16(afr[m][0], bfr[n][0], acc[4 + m][n], 0, 0, 0);
        acc[4 + m][n] = __builtin_amdgcn_mfma_f32_16x16x32_bf16(afr[m][1], bfr[n][1], acc[4 + m][n], 0, 0, 0);
      }
    __builtin_amdgcn_s_setprio(0);
    BARRIER();

    // ---- phase 4: quadrant (mh1,nh1); stage A-h1(t+1)
    if (hn) stage16(A, abase, K, ktn, ag0 + 64, As[nb], lane);
    __builtin_amdgcn_s_setprio(1);
#pragma unroll
    for (int m = 0; m < 4; ++m)
#pragma unroll
      for (int n = 0; n < 2; ++n) {
        acc[4 + m][2 + n] = __builtin_amdgcn_mfma_f32_16x16x32_bf16(afr[m][0], bfr[2 + n][0], acc[4 + m][2 + n], 0, 0, 0);
        acc[4 + m][2 + n] = __builtin_amdgcn_mfma_f32_16x16x32_bf16(afr[m][1], bfr[2 + n][1], acc[4 + m][2 + n], 0, 0, 0);
      }
    __builtin_amdgcn_s_setprio(0);
    if (hn) asm volatile("s_waitcnt vmcnt(4)" ::: "memory");
    BARRIER();

    cur ^= 1;
  }

  const int mat = (int)(bbase >> 11);   // block-uniform (2048 % 256 == 0)
  if (Vt != nullptr && mat == 2) {
#pragma unroll
    for (int m = 0; m < 8; ++m)
#pragma unroll
      for (int n = 0; n < 4; ++n)
#pragma unroll
        for (int r = 0; r < 4; ++r) {
          const long row = abase + wr * 128 + m * 16 + orow + r;
          const int col = (int)bbase + wc * 64 + n * 16 + ocol;
          const int e = col & 2047, hh = e >> 7, dd = e & 127;
          const long bb = row >> 11, ss = row & 2047;
          Vt[(((bb << 4) + hh) * 128 + dd) * 2048 + ss] = bf16bits(acc[m][n][r]);
        }
  } else {
#pragma unroll
    for (int m = 0; m < 8; ++m)
#pragma unroll
      for (int n = 0; n < 4; ++n)
#pragma unroll
        for (int r = 0; r < 4; ++r) {
          const long row = abase + wr * 128 + m * 16 + orow + r;
          const int col = (int)bbase + wc * 64 + n * 16 + ocol;
          const float sc = (mat == 0) ? qs : 1.0f;
          const long idx = (long)mat * matStride + row * 2048 + (col & 2047);
          store_out(Cb, idx, acc[m][n][r] * sc);
        }
  }
}

// ---- 128x256 2-phase bf16 GEMM (O-proj: 8x32 = 256 blocks = 1 round) -----

template <typename OUT_T>
__global__ __launch_bounds__(512, 2) void k_gemm2(const u16* __restrict__ A,
                                                  const u16* __restrict__ Bt,
                                                  OUT_T* __restrict__ Cb,
                                                  int M, int N, int K, long matStride,
                                                  float qs) {
  __shared__ u16 As[2][128][64];
  __shared__ u16 Bs[2][256][64];

  const int tid = threadIdx.x, wid = tid >> 6, lane = tid & 63;
  const int wr = wid >> 2, wc = wid & 3;
  const int frow = lane & 15, fk8 = (lane >> 4) * 8;
  const int orow = (lane >> 4) * 4, ocol = lane & 15;

  const int nwg = gridDim.x * gridDim.y;
  const int orig = blockIdx.y * gridDim.x + blockIdx.x;
  const int q = nwg >> 3, rr = nwg & 7;
  const int xcd = orig & 7, sl = orig >> 3;
  const int wg = (xcd < rr ? xcd * (q + 1) : rr * (q + 1) + (xcd - rr) * q) + sl;
  const int by = wg / gridDim.x, bx = wg % gridDim.x;

  const long abase = (long)by * 128, bbase = (long)bx * 256;

  const int bg0 = (wid >> 1) * 64 + (wid & 1) * 16;
  const int ag0 = ((wid & 1) << 6) + ((wid >> 1) << 3);

  f32x4_t acc[4][4];
#pragma unroll
  for (int m = 0; m < 4; ++m)
#pragma unroll
    for (int n = 0; n < 4; ++n)
#pragma unroll
      for (int r = 0; r < 4; ++r) acc[m][n][r] = 0.f;

  const int nt = K >> 6;

  stage16(Bt, bbase, K, 0, bg0, Bs[0], lane);
  stage16(Bt, bbase, K, 0, bg0 + 32, Bs[0], lane);
  stage8 (A,  abase, K, 0, ag0, As[0], lane);
  stage8 (A,  abase, K, 0, ag0 + 32, As[0], lane);
  asm volatile("s_waitcnt vmcnt(1)" ::: "memory");
  BARRIER();

  bf16x8_t bfr[4][2], afr[2][2];
  int cur = 0;

  for (int t = 0; t < nt; ++t) {
    const int ktn = (t + 1) << 6;
    const bool hn = (t + 1 < nt);
    const int nb = cur ^ 1;

#pragma unroll
    for (int n = 0; n < 4; ++n) {
      const int r = wc * 64 + n * 16 + frow;
      bfr[n][0] = *reinterpret_cast<const bf16x8_t*>(&Bs[cur][r][sw8(r, fk8)]);
      bfr[n][1] = *reinterpret_cast<const bf16x8_t*>(&Bs[cur][r][sw8(r, 32 + fk8)]);
    }
#pragma unroll
    for (int m = 0; m < 2; ++m) {
      const int r = wr * 64 + m * 16 + frow;
      afr[m][0] = *reinterpret_cast<const bf16x8_t*>(&As[cur][r][sw8(r, fk8)]);
      afr[m][1] = *reinterpret_cast<const bf16x8_t*>(&As[cur][r][sw8(r, 32 + fk8)]);
    }
    if (hn) {
      stage16(Bt, bbase, K, ktn, bg0, Bs[nb], lane);
      stage16(Bt, bbase, K, ktn, bg0 + 32, Bs[nb], lane);
    }
    BARRIER();
    WAITLGKM();
    __builtin_amdgcn_s_setprio(1);
#pragma unroll
    for (int m = 0; m < 2; ++m)
#pragma unroll
      for (int n = 0; n < 4; ++n) {
        acc[m][n] = __builtin_amdgcn_mfma_f32_16x16x32_bf16(afr[m][0], bfr[n][0], acc[m][n], 0, 0, 0);
        acc[m][n] = __builtin_amdgcn_mfma_f32_16x16x32_bf16(afr[m][1], bfr[n][1], acc[m][n], 0, 0, 0);
      }
    __builtin_amdgcn_s_setprio(0);
    if (hn) asm volatile("s_waitcnt vmcnt(4)" ::: "memory");
    else    asm volatile("s_waitcnt vmcnt(0)" ::: "memory");
    BARRIER();

#pragma unroll
    for (int m = 0; m < 2; ++m) {
      const int r = wr * 64 + 32 + m * 16 + frow;
      afr[m][0] = *reinterpret_cast<const bf16x8_t*>(&As[cur][r][sw8(r, fk8)]);
      afr[m][1] = *reinterpret_cast<const bf16x8_t*>(&As[cur][r][sw8(r, 32 + fk8)]);
    }
    if (hn) {
      stage8(A, abase, K, ktn, ag0, As[nb], lane);
      stage8(A, abase, K, ktn, ag0 + 32, As[nb], lane);
    }
    BARRIER();
    WAITLGKM();
    __builtin_amdgcn_s_setprio(1);
#pragma unroll
    for (int m = 0; m < 2; ++m)
#pragma unroll
      for (int n = 0; n < 4; ++n) {
        acc[2 + m][n] = __builtin_amdgcn_mfma_f32_16x16x32_bf16(afr[m][0], bfr[n][0], acc[2 + m][n], 0, 0, 0);
        acc[2 + m][n] = __builtin_amdgcn_mfma_f32_16x16x32_bf16(afr[m][1], bfr[n][1], acc[2 + m][n], 0, 0, 0);
      }
    __builtin_amdgcn_s_setprio(0);
    if (hn) asm volatile("s_waitcnt vmcnt(1)" ::: "memory");
    BARRIER();

    cur ^= 1;
  }

#pragma unroll
  for (int m = 0; m < 4; ++m)
#pragma unroll
    for (int n = 0; n < 4; ++n)
#pragma unroll
      for (int r = 0; r < 4; ++r) {
        const long row = abase + wr * 64 + m * 16 + orow + r;
        const int col = (int)bbase + wc * 64 + n * 16 + ocol;
        const float sc = ((col >> 11) == 0) ? qs : 1.0f;
        const long idx = (long)(col >> 11) * matStride + row * 2048 + (col & 2047);
        store_out(Cb, idx, acc[m][n][r] * sc);
      }
}

// ---- flash attention, QBLK=64, log2 softmax, double-buffered K/V (R15) ---

__global__ __launch_bounds__(256) void k_attn(const u16* __restrict__ Q,
                                              const u16* __restrict__ Kb,
                                              const u16* __restrict__ Vt,
                                              u16* __restrict__ Out,
                                              int B, int S, int H, int D,
                                              float log2e) {
  __shared__ u16 Ks[2][64][128];
  __shared__ u16 Vs[2][128][64];
  __shared__ u16 Ps[64][64];

  const int tid = threadIdx.x, wid = tid >> 6, lane = tid & 63;

  const int nq = gridDim.x, nbh = gridDim.y;
  const int lin = blockIdx.x + nq * blockIdx.y;
  const int qb0 = lin / nbh;
  const int bh  = lin % nbh;
  const int qb  = (qb0 < nq / 2) ? qb0 : (nq + nq / 2 - 1 - qb0);

  const int b = bh / H, h = bh % H;
  const int Dh = D / H;

  const float slope2 = alibi_slope(h, H) * log2e;
  const long qrow0 = (long)b * S + qb * 64 + wid * 16;

  const int frow = lane & 15;
  const int fk8  = (lane >> 4) * 8;
  const int orow = (lane >> 4) * 4;
  const int ocol = lane & 15;

  bf16x8_t aq[4];
#pragma unroll
  for (int kk = 0; kk < 4; ++kk)
    aq[kk] = *reinterpret_cast<const bf16x8_t*>(
        Q + (qrow0 + frow) * (long)D + h * Dh + kk * 32 + fk8);

  float cw[4];
#pragma unroll
  for (int n = 0; n < 4; ++n) cw[n] = slope2 * (float)(n * 16 + ocol);

  f32x4_t oacc[8];
#pragma unroll
  for (int no = 0; no < 8; ++no)
#pragma unroll
    for (int r = 0; r < 4; ++r) oacc[no][r] = 0.f;

  float Mrun[4], lrun[4];
#pragma unroll
  for (int r = 0; r < 4; ++r) { Mrun[r] = -3.0e38f; lrun[r] = 0.f; }

  const u16* kbase = Kb + (long)b * S * D + h * Dh;
  const u16* vbase = Vt + (long)bh * Dh * S;

  auto STAGE = [&](int kt, int bi) {
#pragma unroll
    for (int i = 0; i < 4; ++i) {
      const int lr = i * 16 + wid * 4;
      const int r  = lr + (lane >> 4);
      gload_lds16(kbase + ((long)kt * 64 + r) * (long)D + sw8(r, (lane & 15) * 8),
                  &Ks[bi][lr][0]);
    }
#pragma unroll
    for (int i = 0; i < 4; ++i) {
      const int lr = i * 32 + wid * 8;
      const int r  = lr + (lane >> 3);
      gload_lds16(vbase + (long)r * S + kt * 64 + sw8(r, (lane & 7) * 8),
                  &Vs[bi][lr][0]);
    }
  };

  STAGE(qb, 0);
  asm volatile("s_waitcnt vmcnt(0)" ::: "memory");
  BARRIER();

  int cur = 0;

  for (int kt = qb; kt >= 0; --kt) {
    if (kt > 0) STAGE(kt - 1, cur ^ 1);

    f32x4_t sacc[4];
#pragma unroll
    for (int n = 0; n < 4; ++n)
#pragma unroll
      for (int r = 0; r < 4; ++r) sacc[n][r] = 0.f;

    __builtin_amdgcn_s_setprio(1);
#pragma unroll
    for (int kk = 0; kk < 4; ++kk) {
      bf16x8_t bk[4];
#pragma unroll
      for (int n = 0; n < 4; ++n) {
        const int krow = n * 16 + frow;
        bk[n] = *reinterpret_cast<const bf16x8_t*>(&Ks[cur][krow][sw8(krow, kk * 32 + fk8)]);
      }
#pragma unroll
      for (int n = 0; n < 4; ++n)
        sacc[n] = __builtin_amdgcn_mfma_f32_16x16x32_bf16(aq[kk], bk[n], sacc[n], 0, 0, 0);
    }
    __builtin_amdgcn_s_setprio(0);

    const float tb = slope2 * (float)(kt << 6);
    float cbn[4];
#pragma unroll
    for (int n = 0; n < 4; ++n) cbn[n] = tb + cw[n];

    float tmax[4];
#pragma unroll
    for (int r = 0; r < 4; ++r) tmax[r] = -3.0e38f;

    if (kt == qb) {
#pragma unroll
      for (int n = 0; n < 4; ++n)
#pragma unroll
        for (int r = 0; r < 4; ++r) {
          float v = sacc[n][r] + cbn[n];
          v = (n * 16 + ocol <= wid * 16 + orow + r) ? v : -1.0e30f;
          sacc[n][r] = v;
          tmax[r] = fmaxf(tmax[r], v);
        }
    } else {
#pragma unroll
      for (int n = 0; n < 4; ++n)
#pragma unroll
        for (int r = 0; r < 4; ++r) {
          const float v = sacc[n][r] + cbn[n];
          sacc[n][r] = v;
          tmax[r] = fmaxf(tmax[r], v);
        }
    }
#pragma unroll
    for (int r = 0; r < 4; ++r) {
      float t = tmax[r];
      t = fmaxf(t, __shfl_xor(t, 1));
      t = fmaxf(t, __shfl_xor(t, 2));
      t = fmaxf(t, __shfl_xor(t, 4));
      t = fmaxf(t, __shfl_xor(t, 8));
      tmax[r] = t;
    }

    int need = 0;
#pragma unroll
    for (int r = 0; r < 4; ++r) need |= (tmax[r] > Mrun[r] + 11.0f) ? 1 : 0;
    if (__any(need)) {
#pragma unroll
      for (int r = 0; r < 4; ++r) {
        const float mnew = fmaxf(Mrun[r], tmax[r]);
        const float alpha = exp2f(Mrun[r] - mnew);
        Mrun[r] = mnew;
        lrun[r] *= alpha;
#pragma unroll
        for (int no = 0; no < 8; ++no) oacc[no][r] *= alpha;
      }
    }

    float tsum[4];
#pragma unroll
    for (int r = 0; r < 4; ++r) tsum[r] = 0.f;
#pragma unroll
    for (int n = 0; n < 4; ++n)
#pragma unroll
      for (int r = 0; r < 4; ++r) {
        const float p = exp2f(sacc[n][r] - Mrun[r]);
        tsum[r] += p;
        const int prow = wid * 16 + orow + r;
        Ps[prow][sw8(prow, n * 16 + ocol)] = bf16bits(p);
      }
#pragma unroll
    for (int r = 0; r < 4; ++r) {
      float t = tsum[r];
      t += __shfl_xor(t, 1);
      t += __shfl_xor(t, 2);
      t += __shfl_xor(t, 4);
      t += __shfl_xor(t, 8);
      lrun[r] += t;
    }

    WAITLGKM();
    BARRIER();

    __builtin_amdgcn_s_setprio(1);
#pragma unroll
    for (int kk = 0; kk < 2; ++kk) {
      const int prow = wid * 16 + frow;
      bf16x8_t pa = *reinterpret_cast<const bf16x8_t*>(&Ps[prow][sw8(prow, kk * 32 + fk8)]);
#pragma unroll
      for (int no = 0; no < 8; ++no) {
        const int vrow = no * 16 + frow;
        bf16x8_t bv = *reinterpret_cast<const bf16x8_t*>(&Vs[cur][vrow][sw8(vrow, kk * 32 + fk8)]);
        oacc[no] = __builtin_amdgcn_mfma_f32_16x16x32_bf16(pa, bv, oacc[no], 0, 0, 0);
      }
    }
    __builtin_amdgcn_s_setprio(0);

    if (kt > 0) {
      asm volatile("s_waitcnt vmcnt(0)" ::: "memory");
      BARRIER();
      cur ^= 1;
    }
  }

#pragma unroll
  for (int r = 0; r < 4; ++r) {
    const float rl = 1.0f / lrun[r];
    const long trow = qrow0 + orow + r;
#pragma unroll
    for (int no = 0; no < 8; ++no)
      Out[trow * (long)D + h * Dh + no * 16 + ocol] = bf16bits(oacc[no][r] * rl);
  }
}

// ---- launch --------------------------------------------------------------

extern "C" void kernel_launch(void* const* d_in, const int* in_sizes, int n_in,
                              void* d_out, int out_size, void* d_ws, size_t ws_size,
                              hipStream_t stream) {
  const float* hs   = (const float*)d_in[0];
  const float* qkvw = (const float*)d_in[1];
  const float* ow   = (const float*)d_in[2];

  const int D = 2048, B = 2, H = 16;
  const long TD = (long)in_sizes[0];   // T*D = 8388608
  const long DD = (long)in_sizes[2];   // D*D = 4194304
  const int T = (int)(TD / D);         // 4096
  const int S = T / B;                 // 2048
  const int Dh = D / H;                // 128
  const float log2e = 1.44269504f;
  const float qs = (1.0f / sqrtf((float)Dh)) * log2e;  // Q prescale

  u16* ws  = (u16*)d_ws;
  u16* hsb = ws;                  // TD    (later reused as attn)
  u16* wt  = ws + TD;             // 3*DD  (qkv weights^T; +3DD = o-proj^T)
  u16* owt = wt + 3 * DD;         // DD
  u16* qkv = owt + DD;            // 3*TD  [Q | K | Vt]  (Vt fused in GEMM)
  u16* vt   = qkv + 2 * TD;       // Vt[bh][Dh][S] written by QKV epilogue
  u16* attn = hsb;                // TD    (overlay; hsb dead after QKV GEMM)

  // 1) hidden -> bf16
  k_cast_bf16<<<dim3((unsigned)(TD / 1024)), 256, 0, stream>>>(hs, hsb, TD);
  // 2) all weights: cast + transpose in one dispatch (z=0..2: qkvw, z=3: ow)
  k_transpose_cast4<<<dim3(D / 32, D / 32, 4), 256, 0, stream>>>(qkvw, ow, wt, D, D);
  // 3) fused QKV projection + V-transpose epilogue
  k_gemm8<u16><<<dim3((3 * D) / 256, T / 256), 512, 0, stream>>>(
      hsb, wt, qkv, T, 3 * D, D, TD, qs, vt);
  // 4) attention (QBLK=64, log2 domain, descending-k + defer-max + K/V dbuf)
  k_attn<<<dim3(S / 64, B * H), 256, 0, stream>>>(
      qkv, qkv + TD, vt, attn, B, S, H, D, log2e);
  // 5) output projection -> f32 d_out (128x256 tiles: 256 blocks = 1 round)
  k_gemm2<float><<<dim3(D / 256, T / 128), 512, 0, stream>>>(
      attn, owt, (float*)d_out, T, D, D, 0L, 1.0f);
}